// Round 4
// baseline (195.194 us; speedup 1.0000x reference)
//
#include <hip/hip_runtime.h>
#include <math.h>

namespace {
constexpr int BATCH = 4;
constexpr int DDIM  = 128;
constexpr int HDIM  = 192;
constexpr int WDIM  = 192;
constexpr long long NTOT = (long long)BATCH * DDIM * HDIM * WDIM; // 18,874,368
constexpr int GW   = WDIM / 4;            // 48 float4 groups per W-row
constexpr int HS4  = GW;                  // group stride for h +/- 1
constexpr int DS4  = GW * HDIM;           // group stride for d +/- 1 (9216)
constexpr int NDSC = 4 * 1 * 8 * 12 * 12; // 4608
constexpr int BLOCK = 256;
constexpr int DC    = 8;                  // depth steps per thread
constexpr int NCH   = DDIM / DC;          // 16 chunks
constexpr int NCOL  = BATCH * HDIM * GW;  // 36,864 columns
constexpr int NTHREADS = NCOL * NCH;      // 589,824
constexpr int GRID  = NTHREADS / BLOCK;   // 2304 blocks
}

__device__ __forceinline__ float4 ld4(const float* __restrict__ p, long long g) {
    return *(const float4*)(p + 4LL * g);
}

// One thread per (b,h,gw) float4 column x 8 depth steps.
// - D axis: register pipeline (no D-neighbor loads).
// - W axis: neighbors via cross-lane __shfl (lane gw-1 holds 4g-1 as c.w,
//   lane gw+1 holds 4g+4 as c.x). Wave-boundary lanes (0 / 63) patch with a
//   masked 1-lane scalar load. This removes the 64-line-per-inst strided
//   scalar loads that dominated TA line-cycles in R2.
// - np.gradient edges branchless: clamp + scale (1 edge / 0.5 interior).
__global__ __launch_bounds__(BLOCK) void vol_kernel(const float* __restrict__ p,
                                                    const float* __restrict__ y,
                                                    float* __restrict__ part) {
    const int t    = blockIdx.x * BLOCK + threadIdx.x;
    const int lane = threadIdx.x & 63;
    const int gw   = t % GW;
    int rest       = t / GW;
    const int h    = rest % HDIM; rest /= HDIM;
    const int b    = rest % BATCH;
    const int d0   = (rest / BATCH) * DC;

    const int   hmo = (h > 0)        ? HS4 : 0;
    const int   hpo = (h < HDIM - 1) ? HS4 : 0;
    const float sh  = (h == 0 || h == HDIM - 1) ? 1.f : 0.5f;
    const float swx = (gw == 0)      ? 1.f : 0.5f;
    const float sww = (gw == GW - 1) ? 1.f : 0.5f;
    const bool needL = (lane == 0)  && (gw > 0);       // left nbr lives in prev wave
    const bool needR = (lane == 63) && (gw < GW - 1);  // right nbr lives in next wave

    long long g = (((long long)b * DDIM + d0) * HDIM + h) * GW + gw;

    // ---- pipeline init at depth d0 ----
    const long long gm = g - ((d0 > 0) ? DS4 : 0);
    float4 ym = ld4(y, gm), pm = ld4(p, gm);
    float4 yc = ld4(y, g),  pc = ld4(p, g);
    long long gn = g + DS4;                    // d0+1 <= 121 < 128 always
    float4 yn = ld4(y, gn), pn = ld4(p, gn);
    float4 yhm = ld4(y, g - hmo), yhp = ld4(y, g + hpo);
    float4 phm = ld4(p, g - hmo), php = ld4(p, g + hpo);
    float eLy = 0.f, eLp = 0.f, eRy = 0.f, eRp = 0.f;
    if (needL) { eLy = y[4LL * g - 1]; eLp = p[4LL * g - 1]; }
    if (needR) { eRy = y[4LL * g + 4]; eRp = p[4LL * g + 4]; }

    float l1 = 0.f, gd = 0.f;

    #pragma unroll
    for (int i = 0; i < DC; ++i) {
        const int d = d0 + i;

        // ---- prefetch everything for step i+1 (compile-time guard) ----
        float4 ynn, pnn, yhm2, yhp2, phm2, php2;
        float eLy2 = 0.f, eLp2 = 0.f, eRy2 = 0.f, eRp2 = 0.f;
        long long gnn = gn;
        if (i < DC - 1) {
            gnn = gn + ((d + 2 < DDIM) ? DS4 : 0);
            ynn  = ld4(y, gnn);      pnn  = ld4(p, gnn);
            yhm2 = ld4(y, gn - hmo); yhp2 = ld4(y, gn + hpo);
            phm2 = ld4(p, gn - hmo); php2 = ld4(p, gn + hpo);
            if (needL) { eLy2 = y[4LL * gn - 1]; eLp2 = p[4LL * gn - 1]; }
            if (needR) { eRy2 = y[4LL * gn + 4]; eRp2 = p[4LL * gn + 4]; }
        }

        const float sd = (d == 0 || d == DDIM - 1) ? 1.f : 0.5f;

        // ---- W neighbors via cross-lane shuffle + boundary patch + clamp ----
        float Ly = __shfl_up(yc.w, 1, 64);
        float Lp = __shfl_up(pc.w, 1, 64);
        float Ry = __shfl_down(yc.x, 1, 64);
        float Rp = __shfl_down(pc.x, 1, 64);
        Ly = (lane == 0)  ? eLy : Ly;   Ly = gw ? Ly : yc.x;
        Lp = (lane == 0)  ? eLp : Lp;   Lp = gw ? Lp : pc.x;
        Ry = (lane == 63) ? eRy : Ry;   Ry = (gw == GW - 1) ? yc.w : Ry;
        Rp = (lane == 63) ? eRp : Rp;   Rp = (gw == GW - 1) ? pc.w : Rp;

        // ---- L1 ----
        l1 += fabsf(yc.x - pc.x) + fabsf(yc.y - pc.y)
            + fabsf(yc.z - pc.z) + fabsf(yc.w - pc.w);

        float t0, gy, gp;
        // ---- W axis ----
        gy = (yc.y - Ly) * swx;   gp = (pc.y - Lp) * swx;
        t0 = fabsf(gy) - fabsf(gp); gd += t0 * t0;
        gy = (yc.z - yc.x) * 0.5f; gp = (pc.z - pc.x) * 0.5f;
        t0 = fabsf(gy) - fabsf(gp); gd += t0 * t0;
        gy = (yc.w - yc.y) * 0.5f; gp = (pc.w - pc.y) * 0.5f;
        t0 = fabsf(gy) - fabsf(gp); gd += t0 * t0;
        gy = (Ry - yc.z) * sww;   gp = (Rp - pc.z) * sww;
        t0 = fabsf(gy) - fabsf(gp); gd += t0 * t0;

        // ---- H axis ----
        t0 = fabsf((yhp.x - yhm.x) * sh) - fabsf((php.x - phm.x) * sh); gd += t0 * t0;
        t0 = fabsf((yhp.y - yhm.y) * sh) - fabsf((php.y - phm.y) * sh); gd += t0 * t0;
        t0 = fabsf((yhp.z - yhm.z) * sh) - fabsf((php.z - phm.z) * sh); gd += t0 * t0;
        t0 = fabsf((yhp.w - yhm.w) * sh) - fabsf((php.w - phm.w) * sh); gd += t0 * t0;

        // ---- D axis (registers only) ----
        t0 = fabsf((yn.x - ym.x) * sd) - fabsf((pn.x - pm.x) * sd); gd += t0 * t0;
        t0 = fabsf((yn.y - ym.y) * sd) - fabsf((pn.y - pm.y) * sd); gd += t0 * t0;
        t0 = fabsf((yn.z - ym.z) * sd) - fabsf((pn.z - pm.z) * sd); gd += t0 * t0;
        t0 = fabsf((yn.w - ym.w) * sd) - fabsf((pn.w - pm.w) * sd); gd += t0 * t0;

        // ---- shift pipeline ----
        if (i < DC - 1) {
            ym = yc; yc = yn; yn = ynn;
            pm = pc; pc = pn; pn = pnn;
            yhm = yhm2; yhp = yhp2; phm = phm2; php = php2;
            eLy = eLy2; eLp = eLp2; eRy = eRy2; eRp = eRp2;
            g = gn; gn = gnn;
        }
    }

    // ---- block reduction, then one partial pair per block (no atomics) ----
    __shared__ float lds1[4], lds2[4];
    #pragma unroll
    for (int off = 32; off > 0; off >>= 1) {
        l1 += __shfl_down(l1, off, 64);
        gd += __shfl_down(gd, off, 64);
    }
    if ((threadIdx.x & 63) == 0) {
        lds1[threadIdx.x >> 6] = l1;
        lds2[threadIdx.x >> 6] = gd;
    }
    __syncthreads();
    if (threadIdx.x == 0) {
        part[2 * blockIdx.x]     = lds1[0] + lds1[1] + lds1[2] + lds1[3];
        part[2 * blockIdx.x + 1] = lds2[0] + lds2[1] + lds2[2] + lds2[3];
    }
}

// Reduce per-block partials + BCE over the small discriminator tensor.
__global__ __launch_bounds__(BLOCK) void finalize_kernel(const float* __restrict__ dsc,
                                                         const float* __restrict__ part,
                                                         float* __restrict__ out) {
    float l1 = 0.f, gd = 0.f, s = 0.f;
    for (int i = threadIdx.x; i < GRID; i += BLOCK) {
        l1 += part[2 * i];
        gd += part[2 * i + 1];
    }
    for (int i = threadIdx.x; i < NDSC; i += BLOCK) {
        const float x = dsc[i];
        // target is zeros: max(x,0) - x*0 + log1p(exp(-|x|))
        s += fmaxf(x, 0.f) + log1pf(expf(-fabsf(x)));
    }
    __shared__ float a[4], c[4], e[4];
    #pragma unroll
    for (int off = 32; off > 0; off >>= 1) {
        l1 += __shfl_down(l1, off, 64);
        gd += __shfl_down(gd, off, 64);
        s  += __shfl_down(s,  off, 64);
    }
    if ((threadIdx.x & 63) == 0) {
        const int w = threadIdx.x >> 6;
        a[w] = l1; c[w] = gd; e[w] = s;
    }
    __syncthreads();
    if (threadIdx.x == 0) {
        const float bce = (e[0] + e[1] + e[2] + e[3]) / (float)NDSC;
        const float l1m = (a[0] + a[1] + a[2] + a[3]) / (float)NTOT;
        const float gdm = (c[0] + c[1] + c[2] + c[3]) / (float)NTOT;
        out[0] = bce + 100.f * (l1m + gdm);
    }
}

extern "C" void kernel_launch(void* const* d_in, const int* in_sizes, int n_in,
                              void* d_out, int out_size, void* d_ws, size_t ws_size,
                              hipStream_t stream) {
    const float* dsc_fake = (const float*)d_in[0];
    const float* predicts = (const float*)d_in[1];
    const float* y_data   = (const float*)d_in[2];
    // d_in[3] (zeros) unused: target==0 makes the -x*target term vanish.
    float* part = (float*)d_ws;   // GRID*2 floats, fully overwritten each call
    float* out  = (float*)d_out;

    vol_kernel<<<GRID, BLOCK, 0, stream>>>(predicts, y_data, part);
    finalize_kernel<<<1, BLOCK, 0, stream>>>(dsc_fake, part, out);
}